// Round 7
// baseline (165.966 us; speedup 1.0000x reference)
//
#include <hip/hip_runtime.h>
#include <hip/hip_bf16.h>
#include <math.h>

#define TN 1000
#define SPD_EPS 1e-3f

// logm Taylor params: t = (S - M0*I)/R0, spectrum certified in [0.35,1.93]
#define M0 1.16f
#define R0 0.86f
#define BETA 0.7413793103f   // R0/M0

typedef float f32x16 __attribute__((ext_vector_type(16)));
typedef short bf16x8 __attribute__((ext_vector_type(8)));

// W21 = W2 @ W1  : (32x64)@(64x128) -> 32x128
__global__ void w21_kernel(const float* __restrict__ W2, const float* __restrict__ W1,
                           float* __restrict__ W21) {
  int idx = blockIdx.x * 256 + threadIdx.x;
  if (idx < 32 * 128) {
    int c = idx >> 7, k = idx & 127;
    float acc = 0.f;
#pragma unroll 8
    for (int m = 0; m < 64; ++m) acc += W2[c * 64 + m] * W1[m * 128 + k];
    W21[idx] = acc;
  }
}

__device__ __forceinline__ int tix(int r, int c) {  // r <= c, 4x4 upper-tri tile index
  return r * 4 - (r * (r - 1)) / 2 + (c - r);
}

// One block (4 waves, 256 thr) per batch. Waves split the 63 K-steps round-robin,
// each accumulates a partial 128x128 Gram in MFMA accs; merge via Latin-square
// LDS adds; mean-sub; then W21 C W21^T epilogue across all 256 threads.
__global__ __launch_bounds__(256) void cov_kernel(const float* __restrict__ x,
                                                  const float* __restrict__ W21,
                                                  float* __restrict__ S2) {
  const int b = blockIdx.x;
  const int tid = threadIdx.x;
  const int w = tid >> 6;       // wave 0..3
  const int l = tid & 63;
  const int ch = l & 31;
  const int h = l >> 5;

  __shared__ float Ct[10 * 1056];    // 10 tiles [32][33]
  __shared__ float Pl[32 * 130];     // P = W21*C (32x128, padded)
  __shared__ float s_part[4][128];
  __shared__ float s_sh[128];

  for (int idx = tid; idx < 10 * 1056; idx += 256) Ct[idx] = 0.f;

  f32x16 acc00{}, acc01{}, acc02{}, acc03{}, acc11{}, acc12{}, acc13{},
         acc22{}, acc23{}, acc33{};
  float s_own[4] = {0.f, 0.f, 0.f, 0.f};
  bf16x8 fr[4];
  const float* xb = x + (size_t)b * (128 * TN) + (size_t)ch * TN + h * 8;
  float4 sa[8], sb[8];
  const float4 z4 = make_float4(0.f, 0.f, 0.f, 0.f);

#define LOADS(ST, KK) do {                                                   \
    const bool v_ = (16 * (KK) + 8 * h) < TN;                                \
    _Pragma("unroll")                                                        \
    for (int r_ = 0; r_ < 4; ++r_) {                                         \
      const float* p_ = xb + r_ * 32 * TN + 16 * (KK);                       \
      float4 t0_ = z4, t1_ = z4;                                             \
      if (v_) { t0_ = *(const float4*)p_; t1_ = *(const float4*)(p_ + 4); }  \
      ST[2 * r_] = t0_; ST[2 * r_ + 1] = t1_;                                \
    } } while (0)

#define CONVS(ST) do {                                                       \
    _Pragma("unroll")                                                        \
    for (int r_ = 0; r_ < 4; ++r_) {                                         \
      union { bf16x8 v; __hip_bfloat16 e[8]; } u_;                           \
      const float f_[8] = {ST[2*r_].x, ST[2*r_].y, ST[2*r_].z, ST[2*r_].w,   \
                           ST[2*r_+1].x, ST[2*r_+1].y, ST[2*r_+1].z,         \
                           ST[2*r_+1].w};                                    \
      float ss_ = 0.f;                                                       \
      _Pragma("unroll")                                                      \
      for (int i_ = 0; i_ < 8; ++i_) {                                       \
        u_.e[i_] = __float2bfloat16(f_[i_]); ss_ += f_[i_];                  \
      }                                                                      \
      fr[r_] = u_.v; s_own[r_] += ss_;                                       \
    } } while (0)

#define MFMAS() do {                                                         \
    acc00 = __builtin_amdgcn_mfma_f32_32x32x16_bf16(fr[0], fr[0], acc00, 0, 0, 0); \
    acc01 = __builtin_amdgcn_mfma_f32_32x32x16_bf16(fr[0], fr[1], acc01, 0, 0, 0); \
    acc02 = __builtin_amdgcn_mfma_f32_32x32x16_bf16(fr[0], fr[2], acc02, 0, 0, 0); \
    acc03 = __builtin_amdgcn_mfma_f32_32x32x16_bf16(fr[0], fr[3], acc03, 0, 0, 0); \
    acc11 = __builtin_amdgcn_mfma_f32_32x32x16_bf16(fr[1], fr[1], acc11, 0, 0, 0); \
    acc12 = __builtin_amdgcn_mfma_f32_32x32x16_bf16(fr[1], fr[2], acc12, 0, 0, 0); \
    acc13 = __builtin_amdgcn_mfma_f32_32x32x16_bf16(fr[1], fr[3], acc13, 0, 0, 0); \
    acc22 = __builtin_amdgcn_mfma_f32_32x32x16_bf16(fr[2], fr[2], acc22, 0, 0, 0); \
    acc23 = __builtin_amdgcn_mfma_f32_32x32x16_bf16(fr[2], fr[3], acc23, 0, 0, 0); \
    acc33 = __builtin_amdgcn_mfma_f32_32x32x16_bf16(fr[3], fr[3], acc33, 0, 0, 0); \
  } while (0)

  // wave w handles steps w, w+4, ..., < 63 (2 steps per iter; OOB steps zero-masked)
  LOADS(sa, w);
#pragma unroll 1
  for (int s = w; s < 63; s += 8) {
    LOADS(sb, s + 4); CONVS(sa); MFMAS();
    LOADS(sa, s + 8); CONVS(sb); MFMAS();
  }

  // ---- column sums: per-wave partial, then cross-wave combine ----
#pragma unroll
  for (int r = 0; r < 4; ++r) s_own[r] += __shfl_xor(s_own[r], 32);
  if (h == 0) {
#pragma unroll
    for (int r = 0; r < 4; ++r) s_part[w][32 * r + ch] = s_own[r];
  }
  __syncthreads();
  if (tid < 128)
    s_sh[tid] = s_part[0][tid] + s_part[1][tid] + s_part[2][tid] + s_part[3][tid];

  // ---- merge partial Grams: Latin-square (wave w -> tile (s+3w)%10) ----
#define ADD_T(ACC_) do {                                                     \
    float* tp_ = Ct + tlc * 1056;                                            \
    _Pragma("unroll")                                                        \
    for (int p_ = 0; p_ < 16; ++p_) {                                        \
      const int row_ = (p_ & 3) + 8 * (p_ >> 2) + 4 * h;                     \
      tp_[row_ * 33 + ch] += ACC_[p_];                                       \
    } } while (0)

#pragma unroll
  for (int s = 0; s < 10; ++s) {
    const int tlc = (s + 3 * w) % 10;
    switch (tlc) {
      case 0: ADD_T(acc00); break;
      case 1: ADD_T(acc01); break;
      case 2: ADD_T(acc02); break;
      case 3: ADD_T(acc03); break;
      case 4: ADD_T(acc11); break;
      case 5: ADD_T(acc12); break;
      case 6: ADD_T(acc13); break;
      case 7: ADD_T(acc22); break;
      case 8: ADD_T(acc23); break;
      case 9: ADD_T(acc33); break;
    }
    __syncthreads();
  }

  // ---- mean-sub + eps, in place ----
  {
    const int RB[10] = {0, 0, 0, 0, 1, 1, 1, 2, 2, 3};
    const int CB[10] = {0, 1, 2, 3, 1, 2, 3, 2, 3, 3};
#pragma unroll
    for (int tl = 0; tl < 10; ++tl) {
#pragma unroll
      for (int e0 = 0; e0 < 1024; e0 += 256) {
        const int e = e0 + tid;
        const int row = e >> 5, col = e & 31;
        const int Rg = RB[tl] * 32 + row, Cg = CB[tl] * 32 + col;
        float cv = (Ct[tl * 1056 + row * 33 + col]
                    - s_sh[Rg] * s_sh[Cg] * (1.f / TN)) * (1.f / (TN - 1));
        if (Rg == Cg) cv += SPD_EPS;
        Ct[tl * 1056 + row * 33 + col] = cv;
      }
    }
  }
  __syncthreads();

  // ---- P = W21 * C (32x128): thread owns col j, rows [rh*16, rh*16+16) ----
  {
    const int j = tid & 127;
    const int rh = tid >> 7;
    const int cblk = j >> 5;
    float pa[16];
#pragma unroll
    for (int i = 0; i < 16; ++i) pa[i] = 0.f;
#pragma unroll
    for (int kb = 0; kb < 4; ++kb) {
      const bool up = (kb <= cblk);
      const int t1 = up ? tix(kb, cblk) : tix(cblk, kb);
      const int base = t1 * 1056 + (up ? (j & 31) : (j & 31) * 33);
      const int st = up ? 33 : 1;
      const float* wp = W21 + kb * 32;
#pragma unroll 1
      for (int k2 = 0; k2 < 32; ++k2) {
        const float cv = Ct[base + k2 * st];
#pragma unroll
        for (int i = 0; i < 16; ++i)
          pa[i] = fmaf(wp[(rh * 16 + i) * 128 + k2], cv, pa[i]);
      }
    }
#pragma unroll
    for (int i = 0; i < 16; ++i) Pl[(rh * 16 + i) * 130 + j] = pa[i];
  }
  __syncthreads();

  // ---- S2 = P * W21^T (32x32): thread owns col ch2, rows [rg*4, rg*4+4) ----
  {
    const int ch2 = tid & 31;
    const int rg = tid >> 5;   // 0..7
    float sc[4] = {0.f, 0.f, 0.f, 0.f};
    const float* wr = W21 + ch2 * 128;
#pragma unroll 1
    for (int k = 0; k < 128; ++k) {
      const float wv = wr[k];
#pragma unroll
      for (int i = 0; i < 4; ++i)
        sc[i] = fmaf(Pl[(rg * 4 + i) * 130 + k], wv, sc[i]);
    }
    float* So = S2 + ((size_t)b << 10);
#pragma unroll
    for (int i = 0; i < 4; ++i) So[(rg * 4 + i) * 32 + ch2] = sc[i];
  }
}

// ---------------- logm via shifted Taylor + Paterson-Stockmeyer, fused FC ----
// One wave per matrix. Lane (j=l&31, h=l>>5) owns rows [16h,16h+16) of col j.
// NOTE: i-loop unroll capped at 4 — full unroll lets the scheduler hoist all
// 128 ds_read_b128 of the loop-invariant A operand into registers -> spill.
__device__ __forceinline__ void mm_half(float* __restrict__ c,
                                        const float (* __restrict__ A)[36],
                                        const float* __restrict__ bf,
                                        const int r0) {
#pragma unroll 4
  for (int i = 0; i < 16; ++i) {
    const float4* row = (const float4*)(A[r0 + i]);
    float acc = 0.f;
#pragma unroll
    for (int kk = 0; kk < 8; ++kk) {
      const float4 r = row[kk];
      acc = fmaf(r.x, bf[4 * kk + 0], acc);
      acc = fmaf(r.y, bf[4 * kk + 1], acc);
      acc = fmaf(r.z, bf[4 * kk + 2], acc);
      acc = fmaf(r.w, bf[4 * kk + 3], acc);
    }
    c[i] = acc;
  }
}

__device__ __forceinline__ void expand32(float* __restrict__ bf,
                                         const float* __restrict__ v,
                                         const int h) {
#pragma unroll
  for (int i = 0; i < 16; ++i) {
    const float mine = v[i];
    const float other = __shfl_xor(mine, 32);
    bf[i]      = h ? other : mine;
    bf[i + 16] = h ? mine  : other;
  }
}

__global__ __launch_bounds__(64) void logm_fc_kernel(const float* __restrict__ S,
                                                     const float* __restrict__ fcw,
                                                     const float* __restrict__ fcb,
                                                     float* __restrict__ out) {
  const int b = blockIdx.x;
  const int l = threadIdx.x;
  const int j = l & 31;
  const int h = l >> 5;
  const int r0 = h << 4;
  const bool hd = ((j >> 4) == h);
  const int id = j & 15;

  __shared__ float P[6][32][36];   // P[p] = t^(p+1)
  __shared__ float a_sh[44];       // Taylor coeffs a_0..a_41

  if (l < 42) {
    if (l == 0) a_sh[0] = logf(M0);
    else a_sh[l] = ((l & 1) ? 1.f : -1.f) * __powf(BETA, (float)l) / (float)l;
  }

  float cur[16], nxt[16], acc[16], bf[32];
  const float* Sb = S + ((size_t)b << 10);
#pragma unroll
  for (int i = 0; i < 16; ++i) {
    float v = Sb[(r0 + i) * 32 + j] * (1.f / R0);
    if (hd && i == id) v -= (M0 / R0);
    cur[i] = v;
    P[0][r0 + i][j] = v;
  }
  __syncthreads();

  // powers t^2..t^6; unroll 1 so the invariant A operand isn't register-cached
#pragma unroll 1
  for (int p = 1; p < 6; ++p) {
    expand32(bf, cur, h);
    mm_half(nxt, P[0], bf, r0);
#pragma unroll
    for (int i = 0; i < 16; ++i) { cur[i] = nxt[i]; P[p][r0 + i][j] = nxt[i]; }
  }
  __syncthreads();   // powers + coeffs visible

  // ACC = B_6 = a36 I + sum_{p=1..5} a_{36+p} t^p
#pragma unroll
  for (int i = 0; i < 16; ++i) {
    float v = (hd && i == id) ? a_sh[36] : 0.f;
#pragma unroll
    for (int p = 0; p < 5; ++p)
      v = fmaf(a_sh[37 + p], P[p][r0 + i][j], v);
    acc[i] = v;
  }
  // Horner: ACC = u*ACC + B_jj, u = t^6 (LDS, never rewritten); unroll 1 (see above)
#pragma unroll 1
  for (int jj = 5; jj >= 0; --jj) {
    expand32(bf, acc, h);
    mm_half(nxt, P[5], bf, r0);
#pragma unroll
    for (int i = 0; i < 16; ++i) {
      float v = (hd && i == id) ? a_sh[6 * jj] : 0.f;
#pragma unroll
      for (int p = 0; p < 5; ++p)
        v = fmaf(a_sh[6 * jj + 1 + p], P[p][r0 + i][j], v);
      acc[i] = v + nxt[i];
    }
  }

  // ---- fused FC: out[b][k] = fcb[k] + sum_{r,c} L[r][c] * fcw[k][r*32+c] ----
#pragma unroll 2
  for (int k = 0; k < 10; ++k) {
    const float* fw = fcw + (size_t)k * 1024;
    float s = 0.f;
#pragma unroll
    for (int i = 0; i < 16; ++i)
      s = fmaf(acc[i], fw[(r0 + i) * 32 + j], s);
#pragma unroll
    for (int d = 1; d < 64; d <<= 1) s += __shfl_xor(s, d);
    if (l == 0) out[b * 10 + k] = s + fcb[k];
  }
}

extern "C" void kernel_launch(void* const* d_in, const int* in_sizes, int n_in,
                              void* d_out, int out_size, void* d_ws, size_t ws_size,
                              hipStream_t stream) {
  const float* x   = (const float*)d_in[0];
  const float* W1  = (const float*)d_in[1];
  const float* W2  = (const float*)d_in[2];
  const float* fcw = (const float*)d_in[3];
  const float* fcb = (const float*)d_in[4];
  float* out = (float*)d_out;
  char* ws = (char*)d_ws;
  float* W21 = (float*)ws;              // 16 KB
  float* S2  = (float*)(ws + 65536);    // 2 MB

  w21_kernel<<<16, 256, 0, stream>>>(W2, W1, W21);
  cov_kernel<<<512, 256, 0, stream>>>(x, W21, S2);
  logm_fc_kernel<<<512, 64, 0, stream>>>(S2, fcw, fcb, out);
}

// Round 8
// 147.612 us; speedup vs baseline: 1.1243x; 1.1243x over previous
//
#include <hip/hip_runtime.h>
#include <hip/hip_bf16.h>
#include <math.h>

#define TN 1000
#define SPD_EPS 1e-3f

// logm Taylor params: t = (S - M0*I)/R0, spectrum certified in [0.35,1.93]
#define M0 1.16f
#define R0 0.86f
#define BETA 0.7413793103f   // R0/M0

typedef float f32x16 __attribute__((ext_vector_type(16)));
typedef short bf16x8 __attribute__((ext_vector_type(8)));

// W21 = W2 @ W1  : (32x64)@(64x128) -> 32x128
__global__ void w21_kernel(const float* __restrict__ W2, const float* __restrict__ W1,
                           float* __restrict__ W21) {
  int idx = blockIdx.x * 256 + threadIdx.x;
  if (idx < 32 * 128) {
    int c = idx >> 7, k = idx & 127;
    float acc = 0.f;
#pragma unroll 8
    for (int m = 0; m < 64; ++m) acc += W2[c * 64 + m] * W1[m * 128 + k];
    W21[idx] = acc;
  }
}

__device__ __forceinline__ int tix(int r, int c) {  // r <= c, 4x4 upper-tri tile index
  return r * 4 - (r * (r - 1)) / 2 + (c - r);
}

#define YS_STR 68          // bf16 elements per LDS row (136B, 34 dwords)
#define YS_ELE (128 * 68)  // ushorts per buffer
#define PL_OFF 42240       // Ct = 10*1056*4 bytes, then Pl

// One block (4 waves) per batch. Stage x in 16 t-tiles of 64 (coalesced 256B
// row-runs -> bf16 LDS, double-buffered), MFMA partial Grams per wave,
// Latin-square merge, mean-sub, then W21 C W21^T epilogue.
// ys (34.8KB) time-shares smem with Ct+Pl (58.9KB) -> 59.4KB => 2 blocks/CU.
__global__ __launch_bounds__(256) void cov_kernel(const float* __restrict__ x,
                                                  const float* __restrict__ W21,
                                                  float* __restrict__ S2) {
  const int b = blockIdx.x;
  const int tid = threadIdx.x;
  const int w = tid >> 6;       // wave 0..3
  const int l = tid & 63;
  const int ch = l & 31;
  const int h = l >> 5;
  const int g = l & 15;         // float4 index within row-run
  const int rr = l >> 4;        // row within 4-row group (0..3)

  __shared__ __align__(16) char smem[58880];
  __shared__ float s_acc[128];
  ushort* ys = (ushort*)smem;           // [2][128][68] bf16 (main loop only)
  float* Ct = (float*)smem;             // 10 tiles [32][33]   (epilogue)
  float* Pl = (float*)(smem + PL_OFF);  // [32][130]           (epilogue)

  if (tid < 128) s_acc[tid] = 0.f;

  f32x16 acc00{}, acc01{}, acc02{}, acc03{}, acc11{}, acc12{}, acc13{},
         acc22{}, acc23{}, acc33{};
  bf16x8 fr[4];
  float4 st[8];
  const float* xb = x + (size_t)b * (128 * TN);
  const float4 z4 = make_float4(0.f, 0.f, 0.f, 0.f);

  // lane reads float4 #g of row R's 64-float run -> 256B contiguous per row,
  // 4 rows per wave instruction. rem is always a multiple of 8 (1000-64t).
#define CLOAD(TT) do {                                                       \
    const int t0_ = (TT) * 64;                                               \
    const bool v_ = (4 * g) < (TN - t0_);                                    \
    _Pragma("unroll")                                                        \
    for (int rg_ = 0; rg_ < 8; ++rg_) {                                      \
      const int R_ = 32 * w + 4 * rg_ + rr;                                  \
      st[rg_] = v_ ? *(const float4*)(xb + (size_t)R_ * TN + t0_ + 4 * g)    \
                   : z4;                                                     \
    } } while (0)

#define CSTORE(BUF) do {                                                     \
    ushort* yb_ = ys + (BUF) * YS_ELE;                                       \
    _Pragma("unroll")                                                        \
    for (int rg_ = 0; rg_ < 8; ++rg_) {                                      \
      const int R_ = 32 * w + 4 * rg_ + rr;                                  \
      const float4 v_ = st[rg_];                                             \
      float sm_ = v_.x + v_.y + v_.z + v_.w;                                 \
      sm_ += __shfl_xor(sm_, 1); sm_ += __shfl_xor(sm_, 2);                  \
      sm_ += __shfl_xor(sm_, 4); sm_ += __shfl_xor(sm_, 8);                  \
      if (g == 0) s_acc[R_] += sm_;                                          \
      union { ushort4 q; __hip_bfloat16 e[4]; } u_;                          \
      u_.e[0] = __float2bfloat16(v_.x); u_.e[1] = __float2bfloat16(v_.y);    \
      u_.e[2] = __float2bfloat16(v_.z); u_.e[3] = __float2bfloat16(v_.w);    \
      *(ushort4*)(yb_ + R_ * YS_STR + 4 * g) = u_.q;                         \
    } } while (0)

#define MFMAS() do {                                                         \
    acc00 = __builtin_amdgcn_mfma_f32_32x32x16_bf16(fr[0], fr[0], acc00, 0, 0, 0); \
    acc01 = __builtin_amdgcn_mfma_f32_32x32x16_bf16(fr[0], fr[1], acc01, 0, 0, 0); \
    acc02 = __builtin_amdgcn_mfma_f32_32x32x16_bf16(fr[0], fr[2], acc02, 0, 0, 0); \
    acc03 = __builtin_amdgcn_mfma_f32_32x32x16_bf16(fr[0], fr[3], acc03, 0, 0, 0); \
    acc11 = __builtin_amdgcn_mfma_f32_32x32x16_bf16(fr[1], fr[1], acc11, 0, 0, 0); \
    acc12 = __builtin_amdgcn_mfma_f32_32x32x16_bf16(fr[1], fr[2], acc12, 0, 0, 0); \
    acc13 = __builtin_amdgcn_mfma_f32_32x32x16_bf16(fr[1], fr[3], acc13, 0, 0, 0); \
    acc22 = __builtin_amdgcn_mfma_f32_32x32x16_bf16(fr[2], fr[2], acc22, 0, 0, 0); \
    acc23 = __builtin_amdgcn_mfma_f32_32x32x16_bf16(fr[2], fr[3], acc23, 0, 0, 0); \
    acc33 = __builtin_amdgcn_mfma_f32_32x32x16_bf16(fr[3], fr[3], acc33, 0, 0, 0); \
  } while (0)

  // wave w consumes K-slab kk_loc = w of each tile (fragments from LDS)
#define CCONSUME(BUF) do {                                                   \
    const ushort* yb_ = ys + (BUF) * YS_ELE;                                 \
    const int eb_ = 16 * w + 8 * h;                                          \
    _Pragma("unroll")                                                        \
    for (int r_ = 0; r_ < 4; ++r_) {                                         \
      const ushort* p_ = yb_ + (32 * r_ + ch) * YS_STR + eb_;                \
      union { ushort4 q[2]; bf16x8 v; } u_;                                  \
      u_.q[0] = *(const ushort4*)p_;                                         \
      u_.q[1] = *(const ushort4*)(p_ + 4);                                   \
      fr[r_] = u_.v;                                                         \
    }                                                                        \
    MFMAS(); } while (0)

  CLOAD(0);
  __syncthreads();           // s_acc zeroing visible
  CSTORE(0);
  __syncthreads();
#pragma unroll 1
  for (int tt = 0; tt < 16; ++tt) {
    if (tt < 15) CLOAD(tt + 1);      // issue next tile's loads (hide under consume)
    CCONSUME(tt & 1);
    if (tt < 15) CSTORE((tt + 1) & 1);
    __syncthreads();
  }

  // ---- epilogue: ys dead; zero Ct in the same smem ----
  for (int idx = tid; idx < 10 * 1056; idx += 256) Ct[idx] = 0.f;
  __syncthreads();

  // merge partial Grams: Latin-square (wave w -> tile (s+3w)%10)
#define ADD_T(ACC_) do {                                                     \
    float* tp_ = Ct + tlc * 1056;                                            \
    _Pragma("unroll")                                                        \
    for (int p_ = 0; p_ < 16; ++p_) {                                        \
      const int row_ = (p_ & 3) + 8 * (p_ >> 2) + 4 * h;                     \
      tp_[row_ * 33 + ch] += ACC_[p_];                                       \
    } } while (0)

#pragma unroll
  for (int s = 0; s < 10; ++s) {
    const int tlc = (s + 3 * w) % 10;
    switch (tlc) {
      case 0: ADD_T(acc00); break;
      case 1: ADD_T(acc01); break;
      case 2: ADD_T(acc02); break;
      case 3: ADD_T(acc03); break;
      case 4: ADD_T(acc11); break;
      case 5: ADD_T(acc12); break;
      case 6: ADD_T(acc13); break;
      case 7: ADD_T(acc22); break;
      case 8: ADD_T(acc23); break;
      case 9: ADD_T(acc33); break;
    }
    __syncthreads();
  }

  // mean-sub + eps, in place
  {
    const int RB[10] = {0, 0, 0, 0, 1, 1, 1, 2, 2, 3};
    const int CB[10] = {0, 1, 2, 3, 1, 2, 3, 2, 3, 3};
#pragma unroll
    for (int tl = 0; tl < 10; ++tl) {
#pragma unroll
      for (int e0 = 0; e0 < 1024; e0 += 256) {
        const int e = e0 + tid;
        const int row = e >> 5, col = e & 31;
        const int Rg = RB[tl] * 32 + row, Cg = CB[tl] * 32 + col;
        float cv = (Ct[tl * 1056 + row * 33 + col]
                    - s_acc[Rg] * s_acc[Cg] * (1.f / TN)) * (1.f / (TN - 1));
        if (Rg == Cg) cv += SPD_EPS;
        Ct[tl * 1056 + row * 33 + col] = cv;
      }
    }
  }
  __syncthreads();

  // P = W21 * C (32x128): thread owns col j, rows [rh*16, rh*16+16)
  {
    const int j = tid & 127;
    const int rh = tid >> 7;
    const int cblk = j >> 5;
    float pa[16];
#pragma unroll
    for (int i = 0; i < 16; ++i) pa[i] = 0.f;
#pragma unroll
    for (int kb = 0; kb < 4; ++kb) {
      const bool up = (kb <= cblk);
      const int t1 = up ? tix(kb, cblk) : tix(cblk, kb);
      const int base = t1 * 1056 + (up ? (j & 31) : (j & 31) * 33);
      const int stg = up ? 33 : 1;
      const float* wp = W21 + kb * 32;
#pragma unroll 1
      for (int k2 = 0; k2 < 32; ++k2) {
        const float cv = Ct[base + k2 * stg];
#pragma unroll
        for (int i = 0; i < 16; ++i)
          pa[i] = fmaf(wp[(rh * 16 + i) * 128 + k2], cv, pa[i]);
      }
    }
#pragma unroll
    for (int i = 0; i < 16; ++i) Pl[(rh * 16 + i) * 130 + j] = pa[i];
  }
  __syncthreads();

  // S2 = P * W21^T (32x32): thread owns col ch2, rows [rg*4, rg*4+4)
  {
    const int ch2 = tid & 31;
    const int rg = tid >> 5;   // 0..7
    float sc[4] = {0.f, 0.f, 0.f, 0.f};
    const float* wr = W21 + ch2 * 128;
#pragma unroll 1
    for (int k = 0; k < 128; ++k) {
      const float wv = wr[k];
#pragma unroll
      for (int i = 0; i < 4; ++i)
        sc[i] = fmaf(Pl[(rg * 4 + i) * 130 + k], wv, sc[i]);
    }
    float* So = S2 + ((size_t)b << 10);
#pragma unroll
    for (int i = 0; i < 4; ++i) So[(rg * 4 + i) * 32 + ch2] = sc[i];
  }
}

// ---------------- logm via shifted Taylor + Paterson-Stockmeyer, fused FC ----
// One wave per matrix. Lane (j=l&31, h=l>>5) owns rows [16h,16h+16) of col j.
// NOTE: i-loop unroll capped at 4 — full unroll lets the scheduler hoist all
// 128 ds_read_b128 of the loop-invariant A operand into registers -> spill.
__device__ __forceinline__ void mm_half(float* __restrict__ c,
                                        const float (* __restrict__ A)[36],
                                        const float* __restrict__ bf,
                                        const int r0) {
#pragma unroll 4
  for (int i = 0; i < 16; ++i) {
    const float4* row = (const float4*)(A[r0 + i]);
    float acc = 0.f;
#pragma unroll
    for (int kk = 0; kk < 8; ++kk) {
      const float4 r = row[kk];
      acc = fmaf(r.x, bf[4 * kk + 0], acc);
      acc = fmaf(r.y, bf[4 * kk + 1], acc);
      acc = fmaf(r.z, bf[4 * kk + 2], acc);
      acc = fmaf(r.w, bf[4 * kk + 3], acc);
    }
    c[i] = acc;
  }
}

__device__ __forceinline__ void expand32(float* __restrict__ bf,
                                         const float* __restrict__ v,
                                         const int h) {
#pragma unroll
  for (int i = 0; i < 16; ++i) {
    const float mine = v[i];
    const float other = __shfl_xor(mine, 32);
    bf[i]      = h ? other : mine;
    bf[i + 16] = h ? mine  : other;
  }
}

__global__ __launch_bounds__(64) void logm_fc_kernel(const float* __restrict__ S,
                                                     const float* __restrict__ fcw,
                                                     const float* __restrict__ fcb,
                                                     float* __restrict__ out) {
  const int b = blockIdx.x;
  const int l = threadIdx.x;
  const int j = l & 31;
  const int h = l >> 5;
  const int r0 = h << 4;
  const bool hd = ((j >> 4) == h);
  const int id = j & 15;

  __shared__ float P[6][32][36];   // P[p] = t^(p+1)
  __shared__ float a_sh[44];       // Taylor coeffs a_0..a_41

  if (l < 42) {
    if (l == 0) a_sh[0] = logf(M0);
    else a_sh[l] = ((l & 1) ? 1.f : -1.f) * __powf(BETA, (float)l) / (float)l;
  }

  float cur[16], nxt[16], acc[16], bf[32];
  const float* Sb = S + ((size_t)b << 10);
#pragma unroll
  for (int i = 0; i < 16; ++i) {
    float v = Sb[(r0 + i) * 32 + j] * (1.f / R0);
    if (hd && i == id) v -= (M0 / R0);
    cur[i] = v;
    P[0][r0 + i][j] = v;
  }
  __syncthreads();

  // powers t^2..t^6; unroll 1 so the invariant A operand isn't register-cached
#pragma unroll 1
  for (int p = 1; p < 6; ++p) {
    expand32(bf, cur, h);
    mm_half(nxt, P[0], bf, r0);
#pragma unroll
    for (int i = 0; i < 16; ++i) { cur[i] = nxt[i]; P[p][r0 + i][j] = nxt[i]; }
  }
  __syncthreads();   // powers + coeffs visible

  // ACC = B_6 = a36 I + sum_{p=1..5} a_{36+p} t^p
#pragma unroll
  for (int i = 0; i < 16; ++i) {
    float v = (hd && i == id) ? a_sh[36] : 0.f;
#pragma unroll
    for (int p = 0; p < 5; ++p)
      v = fmaf(a_sh[37 + p], P[p][r0 + i][j], v);
    acc[i] = v;
  }
  // Horner: ACC = u*ACC + B_jj, u = t^6 (LDS, never rewritten); unroll 1 (see above)
#pragma unroll 1
  for (int jj = 5; jj >= 0; --jj) {
    expand32(bf, acc, h);
    mm_half(nxt, P[5], bf, r0);
#pragma unroll
    for (int i = 0; i < 16; ++i) {
      float v = (hd && i == id) ? a_sh[6 * jj] : 0.f;
#pragma unroll
      for (int p = 0; p < 5; ++p)
        v = fmaf(a_sh[6 * jj + 1 + p], P[p][r0 + i][j], v);
      acc[i] = v + nxt[i];
    }
  }

  // fused FC: out[b][k] = fcb[k] + sum_{r,c} L[r][c] * fcw[k][r*32+c]
#pragma unroll 2
  for (int k = 0; k < 10; ++k) {
    const float* fw = fcw + (size_t)k * 1024;
    float s = 0.f;
#pragma unroll
    for (int i = 0; i < 16; ++i)
      s = fmaf(acc[i], fw[(r0 + i) * 32 + j], s);
#pragma unroll
    for (int d = 1; d < 64; d <<= 1) s += __shfl_xor(s, d);
    if (l == 0) out[b * 10 + k] = s + fcb[k];
  }
}

extern "C" void kernel_launch(void* const* d_in, const int* in_sizes, int n_in,
                              void* d_out, int out_size, void* d_ws, size_t ws_size,
                              hipStream_t stream) {
  const float* x   = (const float*)d_in[0];
  const float* W1  = (const float*)d_in[1];
  const float* W2  = (const float*)d_in[2];
  const float* fcw = (const float*)d_in[3];
  const float* fcb = (const float*)d_in[4];
  float* out = (float*)d_out;
  char* ws = (char*)d_ws;
  float* W21 = (float*)ws;              // 16 KB
  float* S2  = (float*)(ws + 65536);    // 2 MB

  w21_kernel<<<16, 256, 0, stream>>>(W2, W1, W21);
  cov_kernel<<<512, 256, 0, stream>>>(x, W21, S2);
  logm_fc_kernel<<<512, 64, 0, stream>>>(S2, fcw, fcb, out);
}